// Round 1
// baseline (1107.202 us; speedup 1.0000x reference)
//
#include <hip/hip_runtime.h>
#include <hip/hip_bf16.h>
#include <stdint.h>

#define DIM 128
#define NNODE 100000

typedef __attribute__((ext_vector_type(8))) short short8;
typedef __attribute__((ext_vector_type(4))) float f32x4;

__device__ __forceinline__ unsigned short f32_to_bf16_rne(float f) {
    union { float f; uint32_t u; } v; v.f = f;
    uint32_t u = v.u;
    uint32_t r = u + 0x7FFFu + ((u >> 16) & 1u);
    return (unsigned short)(r >> 16);
}

// ---------------- histogram of dst per relation ----------------
__global__ void hist_kernel(const int* __restrict__ d0, const int* __restrict__ d1,
                            const int* __restrict__ d2, int E0, int E1, int E2,
                            int* __restrict__ cnt, int N) {
    int i = blockIdx.x * blockDim.x + threadIdx.x;
    int total = E0 + E1 + E2;
    if (i >= total) return;
    int rel, e; const int* d;
    if (i < E0)            { rel = 0; e = i;           d = d0; }
    else if (i < E0 + E1)  { rel = 1; e = i - E0;      d = d1; }
    else                   { rel = 2; e = i - E0 - E1; d = d2; }
    atomicAdd(&cnt[rel * N + d[e]], 1);
}

// ---------------- per-relation exclusive scan (1 block per relation) ----------------
__global__ void scan_kernel(const int* __restrict__ cnt, int* __restrict__ off,
                            int* __restrict__ cur, int N) {
    __shared__ int sdata[1024];
    __shared__ int s_carry;
    const int base = blockIdx.x * N;
    const int tid = threadIdx.x;
    if (tid == 0) s_carry = 0;
    __syncthreads();
    const int CH = 8 * 1024;
    for (int chunk = 0; chunk < N; chunk += CH) {
        int v[8]; int local = 0;
        int i0 = chunk + tid * 8;
        #pragma unroll
        for (int j = 0; j < 8; j++) {
            int i = i0 + j;
            v[j] = (i < N) ? cnt[base + i] : 0;
            local += v[j];
        }
        sdata[tid] = local;
        __syncthreads();
        for (int s = 1; s < 1024; s <<= 1) {
            int t = (tid >= s) ? sdata[tid - s] : 0;
            __syncthreads();
            sdata[tid] += t;
            __syncthreads();
        }
        int incl = sdata[tid];
        int carry = s_carry;
        __syncthreads();                    // everyone has read s_carry
        if (tid == 1023) s_carry = carry + incl;  // incl of last thread == chunk total
        int excl = incl - local + carry;
        #pragma unroll
        for (int j = 0; j < 8; j++) {
            int i = i0 + j;
            if (i < N) { off[base + i] = excl; cur[base + i] = excl; }
            excl += v[j];
        }
        __syncthreads();
    }
}

// ---------------- scatter src ids into dst-bucketed order ----------------
__global__ void scatter_kernel(const int* __restrict__ ei0, const int* __restrict__ ei1,
                               const int* __restrict__ ei2, int E0, int E1, int E2,
                               int* __restrict__ cur, int* __restrict__ sorted, int N) {
    int i = blockIdx.x * blockDim.x + threadIdx.x;
    int total = E0 + E1 + E2;
    if (i >= total) return;
    int rel, e, E, sbase; const int* ei;
    if (i < E0)           { rel = 0; e = i;           ei = ei0; E = E0; sbase = 0; }
    else if (i < E0 + E1) { rel = 1; e = i - E0;      ei = ei1; E = E1; sbase = E0; }
    else                  { rel = 2; e = i - E0 - E1; ei = ei2; E = E2; sbase = E0 + E1; }
    int s = ei[e];
    int d = ei[E + e];
    int pos = atomicAdd(&cur[rel * N + d], 1);
    sorted[sbase + pos] = s;
}

// ---------------- segment mean: one wave per dst node, bf16 output ----------------
__global__ __launch_bounds__(256) void agg_kernel(
    const float* __restrict__ x_user, const float* __restrict__ x_item,
    const float* __restrict__ x_tag,
    const int* __restrict__ sorted, const int* __restrict__ off,
    const int* __restrict__ cnt, int E0, int E01,
    unsigned short* __restrict__ msg, int N) {
    int w = (blockIdx.x * blockDim.x + threadIdx.x) >> 6;
    int lane = threadIdx.x & 63;
    if (w >= 3 * N) return;
    int rel = w / N;
    int d = w - rel * N;
    const float* xs = (rel == 0) ? x_user : (rel == 1) ? x_item : x_tag;
    int sbase = (rel == 0) ? 0 : (rel == 1) ? E0 : E01;
    int start = off[rel * N + d];
    int deg = cnt[rel * N + d];
    const int* lst = sorted + sbase + start;
    float2 acc = make_float2(0.f, 0.f);
    for (int i = 0; i < deg; i++) {
        int s = lst[i];                         // wave-uniform broadcast load
        const float2* row = (const float2*)(xs + (size_t)s * DIM);
        float2 vv = row[lane];                  // coalesced: 512B per row per wave
        acc.x += vv.x; acc.y += vv.y;
    }
    float inv = 1.0f / (float)max(deg, 1);
    acc.x *= inv; acc.y *= inv;
    ushort2 o;
    o.x = f32_to_bf16_rne(acc.x);
    o.y = f32_to_bf16_rne(acc.y);
    *(ushort2*)(msg + ((size_t)(rel * N + d)) * DIM + lane * 2) = o;
}

// ---------------- pack weights into MFMA B-fragment order (bf16) + biases ----------------
// pw layout: elem index = (((ks*8 + nt)*64 + lane)*8 + j)
//   k_local = (ks&3)*32 + (lane>>4)*8 + j ; n = nt*16 + (lane&15) ; src = ks>>2
__global__ void pack_kernel(const float* __restrict__ Wl_b, const float* __restrict__ Wr_b,
                            const float* __restrict__ b_b,
                            const float* __restrict__ Wl_r, const float* __restrict__ Wr_r,
                            const float* __restrict__ b_r,
                            const float* __restrict__ Wl_t, const float* __restrict__ Wr_t,
                            const float* __restrict__ b_t,
                            unsigned short* __restrict__ pw_item,
                            unsigned short* __restrict__ pw_user,
                            float* __restrict__ bias_item, float* __restrict__ bias_user) {
    const int NI = 12 * 8 * 64 * 8;   // 49152 (item: K=384)
    const int NU = 8 * 8 * 64 * 8;    // 32768 (user: K=256)
    int o = blockIdx.x * blockDim.x + threadIdx.x;
    if (o < NI) {
        int j = o & 7, lane = (o >> 3) & 63, ks = o >> 12;
        int n = ((o >> 9) & 7) * 16 + (lane & 15);
        int k = (ks & 3) * 32 + (lane >> 4) * 8 + j;
        int src = ks >> 2;
        float v;
        if (src == 0)      v = 0.5f * Wl_b[k * DIM + n];
        else if (src == 1) v = 0.5f * Wl_t[k * DIM + n];
        else               v = 0.5f * (Wr_b[k * DIM + n] + Wr_t[k * DIM + n]);
        pw_item[o] = f32_to_bf16_rne(v);
    } else if (o < NI + NU) {
        int oo = o - NI;
        int j = oo & 7, lane = (oo >> 3) & 63, ks = oo >> 12;
        int n = ((oo >> 9) & 7) * 16 + (lane & 15);
        int k = (ks & 3) * 32 + (lane >> 4) * 8 + j;
        float v = ((ks >> 2) == 0) ? Wl_r[k * DIM + n] : Wr_r[k * DIM + n];
        pw_user[oo] = f32_to_bf16_rne(v);
    } else {
        int oo = o - NI - NU;
        if (oo < DIM)            bias_item[oo] = 0.5f * (b_b[oo] + b_t[oo]);
        else if (oo < 2 * DIM)   bias_user[oo - DIM] = b_r[oo - DIM];
    }
}

// ---------------- fused GEMM: out = [A0|A1|Xf] @ packW + bias ----------------
// block = 4 waves, each wave: 16 rows x 128 cols. A-frag: m=lane&15, k=quad*8+j.
// C/D: col=lane&15, row=quad*4+reg (verified layouts).
__global__ __launch_bounds__(256) void gemm_kernel(
    const unsigned short* __restrict__ Abf0,
    const unsigned short* __restrict__ Abf1,
    const float* __restrict__ Af32,
    int n_bf,
    const unsigned short* __restrict__ packW,
    const float* __restrict__ bias,
    float* __restrict__ out, int M) {
    int wave = threadIdx.x >> 6;
    int lane = threadIdx.x & 63;
    int quad = lane >> 4;
    int l15  = lane & 15;
    int m0   = blockIdx.x * 64 + wave * 16;
    int arow = m0 + l15;
    bool arow_ok = arow < M;
    int nks = (n_bf + 1) * 4;

    f32x4 acc[8];
    #pragma unroll
    for (int i = 0; i < 8; i++) acc[i] = (f32x4){0.f, 0.f, 0.f, 0.f};

    for (int ks = 0; ks < nks; ks++) {
        int src = ks >> 2;
        int kofs = (ks & 3) * 32 + quad * 8;
        short8 afrag;
        if (src < n_bf) {
            const unsigned short* A = (src == 0) ? Abf0 : Abf1;
            if (arow_ok) afrag = *(const short8*)(A + (size_t)arow * DIM + kofs);
            else         afrag = (short8){0,0,0,0,0,0,0,0};
        } else {
            if (arow_ok) {
                const float* p = Af32 + (size_t)arow * DIM + kofs;
                float4 f0 = *(const float4*)(p);
                float4 f1 = *(const float4*)(p + 4);
                afrag = (short8){
                    (short)f32_to_bf16_rne(f0.x), (short)f32_to_bf16_rne(f0.y),
                    (short)f32_to_bf16_rne(f0.z), (short)f32_to_bf16_rne(f0.w),
                    (short)f32_to_bf16_rne(f1.x), (short)f32_to_bf16_rne(f1.y),
                    (short)f32_to_bf16_rne(f1.z), (short)f32_to_bf16_rne(f1.w)};
            } else afrag = (short8){0,0,0,0,0,0,0,0};
        }
        const unsigned short* wp = packW + ((size_t)ks * 8 * 64 + lane) * 8;
        #pragma unroll
        for (int nt = 0; nt < 8; nt++) {
            short8 wfrag = *(const short8*)(wp + (size_t)nt * 64 * 8);
            acc[nt] = __builtin_amdgcn_mfma_f32_16x16x32_bf16(afrag, wfrag, acc[nt], 0, 0, 0);
        }
    }
    #pragma unroll
    for (int nt = 0; nt < 8; nt++) {
        int col = nt * 16 + l15;
        float bv = bias[col];
        #pragma unroll
        for (int r = 0; r < 4; r++) {
            int row = m0 + quad * 4 + r;
            if (row < M) out[(size_t)row * DIM + col] = acc[nt][r] + bv;
        }
    }
}

extern "C" void kernel_launch(void* const* d_in, const int* in_sizes, int n_in,
                              void* d_out, int out_size, void* d_ws, size_t ws_size,
                              hipStream_t stream) {
    const float* x_user = (const float*)d_in[0];
    const float* x_item = (const float*)d_in[1];
    const float* x_tag  = (const float*)d_in[2];
    const int* ei_buys  = (const int*)d_in[3];
    const int* ei_rev   = (const int*)d_in[4];
    const int* ei_tags  = (const int*)d_in[5];
    const float* Wl_b = (const float*)d_in[6];
    const float* Wr_b = (const float*)d_in[7];
    const float* b_b  = (const float*)d_in[8];
    const float* Wl_r = (const float*)d_in[9];
    const float* Wr_r = (const float*)d_in[10];
    const float* b_r  = (const float*)d_in[11];
    const float* Wl_t = (const float*)d_in[12];
    const float* Wr_t = (const float*)d_in[13];
    const float* b_t  = (const float*)d_in[14];

    const int N  = NNODE;
    const int E0 = in_sizes[3] / 2, E1 = in_sizes[4] / 2, E2 = in_sizes[5] / 2;

    // workspace layout (bytes)
    char* w = (char*)d_ws;
    int* cnt    = (int*)(w + 0);           // 3*N*4       = 1,200,000
    int* off    = (int*)(w + 1200000);     // 1,200,000
    int* cur    = (int*)(w + 2400000);     // 1,200,000
    int* sorted = (int*)(w + 3600000);     // (E0+E1+E2)*4 = 12,000,000
    unsigned short* msg = (unsigned short*)(w + 15600000);      // 3*N*128*2 = 76,800,000
    unsigned short* pw_item = (unsigned short*)(w + 92400000);  // 98,304
    unsigned short* pw_user = (unsigned short*)(w + 92498304);  // 65,536
    float* bias_item = (float*)(w + 92563840);                  // 512
    float* bias_user = (float*)(w + 92564352);                  // 512  (total ~88.3 MB)

    float* out_user = (float*)d_out;
    float* out_item = out_user + (size_t)N * DIM;

    int Etot = E0 + E1 + E2;

    hipMemsetAsync(cnt, 0, (size_t)3 * N * sizeof(int), stream);

    pack_kernel<<<(49152 + 32768 + 2 * DIM + 255) / 256, 256, 0, stream>>>(
        Wl_b, Wr_b, b_b, Wl_r, Wr_r, b_r, Wl_t, Wr_t, b_t,
        pw_item, pw_user, bias_item, bias_user);

    hist_kernel<<<(Etot + 255) / 256, 256, 0, stream>>>(
        ei_buys + E0, ei_rev + E1, ei_tags + E2, E0, E1, E2, cnt, N);

    scan_kernel<<<3, 1024, 0, stream>>>(cnt, off, cur, N);

    scatter_kernel<<<(Etot + 255) / 256, 256, 0, stream>>>(
        ei_buys, ei_rev, ei_tags, E0, E1, E2, cur, sorted, N);

    agg_kernel<<<(3 * N * 64 + 255) / 256, 256, 0, stream>>>(
        x_user, x_item, x_tag, sorted, off, cnt, E0, E0 + E1, msg, N);

    // out_item = msg_buys@(.5Wl_b) + msg_tags@(.5Wl_t) + x_item@(.5(Wr_b+Wr_t)) + .5(b_b+b_t)
    gemm_kernel<<<(N + 63) / 64, 256, 0, stream>>>(
        msg, msg + 2 * (size_t)N * DIM, x_item, 2, pw_item, bias_item, out_item, N);

    // out_user = msg_rev@Wl_r + x_user@Wr_r + b_r
    gemm_kernel<<<(N + 63) / 64, 256, 0, stream>>>(
        msg + (size_t)N * DIM, nullptr, x_user, 1, pw_user, bias_user, out_user, N);
}

// Round 2
// 927.209 us; speedup vs baseline: 1.1941x; 1.1941x over previous
//
#include <hip/hip_runtime.h>
#include <hip/hip_bf16.h>
#include <stdint.h>

#define DIM 128
#define NNODE 100000

typedef __attribute__((ext_vector_type(8))) short short8;
typedef __attribute__((ext_vector_type(4))) float f32x4;

__device__ __forceinline__ unsigned short f32_to_bf16_rne(float f) {
    union { float f; uint32_t u; } v; v.f = f;
    uint32_t u = v.u;
    uint32_t r = u + 0x7FFFu + ((u >> 16) & 1u);
    return (unsigned short)(r >> 16);
}
__device__ __forceinline__ float bf16_to_f32(unsigned short u) {
    union { uint32_t i; float f; } v; v.i = ((uint32_t)u) << 16; return v.f;
}

// ---------------- f32 -> bf16 table conversion ----------------
__global__ void conv_kernel(const float* __restrict__ xu, const float* __restrict__ xi,
                            const float* __restrict__ xt,
                            unsigned short* __restrict__ bu, unsigned short* __restrict__ bi,
                            unsigned short* __restrict__ bt, int nu, int ni, int nt) {
    int idx = blockIdx.x * blockDim.x + threadIdx.x;     // one float4 per thread
    int q_u = nu >> 2, q_i = ni >> 2, q_t = nt >> 2;
    const float* src; unsigned short* dst; int o;
    if (idx < q_u)                { src = xu; dst = bu; o = idx; }
    else if (idx < q_u + q_i)     { src = xi; dst = bi; o = idx - q_u; }
    else if (idx < q_u + q_i+q_t) { src = xt; dst = bt; o = idx - q_u - q_i; }
    else return;
    float4 f = ((const float4*)src)[o];
    ushort4 u;
    u.x = f32_to_bf16_rne(f.x); u.y = f32_to_bf16_rne(f.y);
    u.z = f32_to_bf16_rne(f.z); u.w = f32_to_bf16_rne(f.w);
    ((ushort4*)dst)[o] = u;
}

// ---------------- histogram of dst per relation ----------------
__global__ void hist_kernel(const int* __restrict__ d0, const int* __restrict__ d1,
                            const int* __restrict__ d2, int E0, int E1, int E2,
                            int* __restrict__ cnt, int N) {
    int i = blockIdx.x * blockDim.x + threadIdx.x;
    int total = E0 + E1 + E2;
    if (i >= total) return;
    int rel, e; const int* d;
    if (i < E0)            { rel = 0; e = i;           d = d0; }
    else if (i < E0 + E1)  { rel = 1; e = i - E0;      d = d1; }
    else                   { rel = 2; e = i - E0 - E1; d = d2; }
    atomicAdd(&cnt[rel * N + d[e]], 1);
}

// ---------------- per-relation exclusive scan (1 block/relation, wave-shuffle) ------
__global__ __launch_bounds__(1024) void scan_kernel(const int* __restrict__ cnt,
                                                    int* __restrict__ off,
                                                    int* __restrict__ cur, int N) {
    __shared__ int wsum[16];
    __shared__ int s_carry;
    const int base = blockIdx.x * N;
    const int tid = threadIdx.x;
    const int lane = tid & 63;
    const int wid = tid >> 6;
    if (tid == 0) s_carry = 0;
    __syncthreads();
    const int CH = 8 * 1024;
    for (int chunk = 0; chunk < N; chunk += CH) {
        int v[8]; int local = 0;
        int i0 = chunk + tid * 8;
        #pragma unroll
        for (int j = 0; j < 8; j++) {
            int i = i0 + j;
            v[j] = (i < N) ? cnt[base + i] : 0;
            local += v[j];
        }
        int incl = local;
        #pragma unroll
        for (int s = 1; s < 64; s <<= 1) {
            int t = __shfl_up(incl, s, 64);
            if (lane >= s) incl += t;
        }
        if (lane == 63) wsum[wid] = incl;
        __syncthreads();
        int wprefix = 0;
        for (int k = 0; k < wid; k++) wprefix += wsum[k];
        int carry = s_carry;
        __syncthreads();
        if (tid == 1023) s_carry = carry + wprefix + incl;
        int excl = carry + wprefix + incl - local;
        #pragma unroll
        for (int j = 0; j < 8; j++) {
            int i = i0 + j;
            if (i < N) { off[base + i] = excl; cur[base + i] = excl; }
            excl += v[j];
        }
        __syncthreads();
    }
}

// ---------------- scatter src ids into dst-bucketed order ----------------
__global__ void scatter_kernel(const int* __restrict__ ei0, const int* __restrict__ ei1,
                               const int* __restrict__ ei2, int E0, int E1, int E2,
                               int* __restrict__ cur, int* __restrict__ sorted, int N) {
    int i = blockIdx.x * blockDim.x + threadIdx.x;
    int total = E0 + E1 + E2;
    if (i >= total) return;
    int rel, e, E, sbase; const int* ei;
    if (i < E0)           { rel = 0; e = i;           ei = ei0; E = E0; sbase = 0; }
    else if (i < E0 + E1) { rel = 1; e = i - E0;      ei = ei1; E = E1; sbase = E0; }
    else                  { rel = 2; e = i - E0 - E1; ei = ei2; E = E2; sbase = E0 + E1; }
    int s = ei[e];
    int d = ei[E + e];
    int pos = atomicAdd(&cur[rel * N + d], 1);
    sorted[sbase + pos] = s;
}

// ---------------- segment mean (bf16 tables): one wave per dst node ----------------
// Half-wave h = lane>>5 handles neighbor i+h; unroll 2 pairs -> 4 rows in flight.
__global__ __launch_bounds__(256) void agg_kernel_bf16(
    const unsigned short* __restrict__ xb_user, const unsigned short* __restrict__ xb_item,
    const unsigned short* __restrict__ xb_tag,
    const int* __restrict__ sorted, const int* __restrict__ off,
    const int* __restrict__ cnt, int E0, int E01,
    unsigned short* __restrict__ msg, int N) {
    int w = (blockIdx.x * blockDim.x + threadIdx.x) >> 6;
    int lane = threadIdx.x & 63;
    if (w >= 3 * N) return;
    int rel = w / N;
    int d = w - rel * N;
    const unsigned short* xs = (rel == 0) ? xb_user : (rel == 1) ? xb_item : xb_tag;
    int sbase = (rel == 0) ? 0 : (rel == 1) ? E0 : E01;
    int start = off[rel * N + d];
    int deg = cnt[rel * N + d];
    const int* lst = sorted + sbase + start;
    int h = lane >> 5;        // half id: neighbor parity
    int c = lane & 31;        // column group: cols 4c..4c+3
    f32x4 acc = (f32x4){0.f, 0.f, 0.f, 0.f};
    int i = 0;
    for (; i + 4 <= deg; i += 4) {
        int s0 = lst[i + h];
        int s1 = lst[i + 2 + h];
        ushort4 u0 = *(const ushort4*)(xs + (size_t)s0 * DIM + c * 4);
        ushort4 u1 = *(const ushort4*)(xs + (size_t)s1 * DIM + c * 4);
        acc[0] += bf16_to_f32(u0.x); acc[1] += bf16_to_f32(u0.y);
        acc[2] += bf16_to_f32(u0.z); acc[3] += bf16_to_f32(u0.w);
        acc[0] += bf16_to_f32(u1.x); acc[1] += bf16_to_f32(u1.y);
        acc[2] += bf16_to_f32(u1.z); acc[3] += bf16_to_f32(u1.w);
    }
    int rem = deg - i;        // 0..3
    if (h < rem) {
        int s = lst[i + h];
        ushort4 u = *(const ushort4*)(xs + (size_t)s * DIM + c * 4);
        acc[0] += bf16_to_f32(u.x); acc[1] += bf16_to_f32(u.y);
        acc[2] += bf16_to_f32(u.z); acc[3] += bf16_to_f32(u.w);
    }
    if (h + 2 < rem) {        // rem==3: extra neighbor for half 0
        int s = lst[i + h + 2];
        ushort4 u = *(const ushort4*)(xs + (size_t)s * DIM + c * 4);
        acc[0] += bf16_to_f32(u.x); acc[1] += bf16_to_f32(u.y);
        acc[2] += bf16_to_f32(u.z); acc[3] += bf16_to_f32(u.w);
    }
    #pragma unroll
    for (int k = 0; k < 4; k++) acc[k] += __shfl_xor(acc[k], 32, 64);
    float inv = 1.0f / (float)max(deg, 1);
    if (h == 0) {
        ushort4 o;
        o.x = f32_to_bf16_rne(acc[0] * inv); o.y = f32_to_bf16_rne(acc[1] * inv);
        o.z = f32_to_bf16_rne(acc[2] * inv); o.w = f32_to_bf16_rne(acc[3] * inv);
        *(ushort4*)(msg + (size_t)(rel * N + d) * DIM + c * 4) = o;
    }
}

// ---------------- segment mean (f32 tables) fallback, same structure ----------------
__global__ __launch_bounds__(256) void agg_kernel_f32(
    const float* __restrict__ x_user, const float* __restrict__ x_item,
    const float* __restrict__ x_tag,
    const int* __restrict__ sorted, const int* __restrict__ off,
    const int* __restrict__ cnt, int E0, int E01,
    unsigned short* __restrict__ msg, int N) {
    int w = (blockIdx.x * blockDim.x + threadIdx.x) >> 6;
    int lane = threadIdx.x & 63;
    if (w >= 3 * N) return;
    int rel = w / N;
    int d = w - rel * N;
    const float* xs = (rel == 0) ? x_user : (rel == 1) ? x_item : x_tag;
    int sbase = (rel == 0) ? 0 : (rel == 1) ? E0 : E01;
    int start = off[rel * N + d];
    int deg = cnt[rel * N + d];
    const int* lst = sorted + sbase + start;
    int h = lane >> 5;
    int c = lane & 31;
    f32x4 acc = (f32x4){0.f, 0.f, 0.f, 0.f};
    int i = 0;
    for (; i + 4 <= deg; i += 4) {
        int s0 = lst[i + h];
        int s1 = lst[i + 2 + h];
        f32x4 v0 = *(const f32x4*)(xs + (size_t)s0 * DIM + c * 4);
        f32x4 v1 = *(const f32x4*)(xs + (size_t)s1 * DIM + c * 4);
        acc += v0; acc += v1;
    }
    int rem = deg - i;
    if (h < rem) {
        int s = lst[i + h];
        acc += *(const f32x4*)(xs + (size_t)s * DIM + c * 4);
    }
    if (h + 2 < rem) {
        int s = lst[i + h + 2];
        acc += *(const f32x4*)(xs + (size_t)s * DIM + c * 4);
    }
    #pragma unroll
    for (int k = 0; k < 4; k++) acc[k] += __shfl_xor(acc[k], 32, 64);
    float inv = 1.0f / (float)max(deg, 1);
    if (h == 0) {
        ushort4 o;
        o.x = f32_to_bf16_rne(acc[0] * inv); o.y = f32_to_bf16_rne(acc[1] * inv);
        o.z = f32_to_bf16_rne(acc[2] * inv); o.w = f32_to_bf16_rne(acc[3] * inv);
        *(ushort4*)(msg + (size_t)(rel * N + d) * DIM + c * 4) = o;
    }
}

// ---------------- pack weights into MFMA B-fragment order (bf16) + biases ----------------
__global__ void pack_kernel(const float* __restrict__ Wl_b, const float* __restrict__ Wr_b,
                            const float* __restrict__ b_b,
                            const float* __restrict__ Wl_r, const float* __restrict__ Wr_r,
                            const float* __restrict__ b_r,
                            const float* __restrict__ Wl_t, const float* __restrict__ Wr_t,
                            const float* __restrict__ b_t,
                            unsigned short* __restrict__ pw_item,
                            unsigned short* __restrict__ pw_user,
                            float* __restrict__ bias_item, float* __restrict__ bias_user) {
    const int NI = 12 * 8 * 64 * 8;   // item: K=384
    const int NU = 8 * 8 * 64 * 8;    // user: K=256
    int o = blockIdx.x * blockDim.x + threadIdx.x;
    if (o < NI) {
        int j = o & 7, lane = (o >> 3) & 63, ks = o >> 12;
        int n = ((o >> 9) & 7) * 16 + (lane & 15);
        int k = (ks & 3) * 32 + (lane >> 4) * 8 + j;
        int src = ks >> 2;
        float v;
        if (src == 0)      v = 0.5f * Wl_b[k * DIM + n];
        else if (src == 1) v = 0.5f * Wl_t[k * DIM + n];
        else               v = 0.5f * (Wr_b[k * DIM + n] + Wr_t[k * DIM + n]);
        pw_item[o] = f32_to_bf16_rne(v);
    } else if (o < NI + NU) {
        int oo = o - NI;
        int j = oo & 7, lane = (oo >> 3) & 63, ks = oo >> 12;
        int n = ((oo >> 9) & 7) * 16 + (lane & 15);
        int k = (ks & 3) * 32 + (lane >> 4) * 8 + j;
        float v = ((ks >> 2) == 0) ? Wl_r[k * DIM + n] : Wr_r[k * DIM + n];
        pw_user[oo] = f32_to_bf16_rne(v);
    } else {
        int oo = o - NI - NU;
        if (oo < DIM)            bias_item[oo] = 0.5f * (b_b[oo] + b_t[oo]);
        else if (oo < 2 * DIM)   bias_user[oo - DIM] = b_r[oo - DIM];
    }
}

// ---------------- fused GEMM: out = [A0|A1|A2] @ packW + bias ----------------
// block = 4 waves, each wave: 16 rows x 128 cols. A-frag: m=lane&15, k=quad*8+j.
// C/D: col=lane&15, row=quad*4+reg (verified layouts).
__global__ __launch_bounds__(256) void gemm_kernel(
    const unsigned short* __restrict__ Abf0,
    const unsigned short* __restrict__ Abf1,
    const unsigned short* __restrict__ Abf2,
    const float* __restrict__ Af32,
    int n_bf, int n_src,
    const unsigned short* __restrict__ packW,
    const float* __restrict__ bias,
    float* __restrict__ out, int M) {
    int wave = threadIdx.x >> 6;
    int lane = threadIdx.x & 63;
    int quad = lane >> 4;
    int l15  = lane & 15;
    int m0   = blockIdx.x * 64 + wave * 16;
    int arow = m0 + l15;
    bool arow_ok = arow < M;
    int nks = n_src * 4;

    f32x4 acc[8];
    #pragma unroll
    for (int i = 0; i < 8; i++) acc[i] = (f32x4){0.f, 0.f, 0.f, 0.f};

    for (int ks = 0; ks < nks; ks++) {
        int src = ks >> 2;
        int kofs = (ks & 3) * 32 + quad * 8;
        short8 afrag;
        if (src < n_bf) {
            const unsigned short* A = (src == 0) ? Abf0 : (src == 1) ? Abf1 : Abf2;
            if (arow_ok) afrag = *(const short8*)(A + (size_t)arow * DIM + kofs);
            else         afrag = (short8){0,0,0,0,0,0,0,0};
        } else {
            if (arow_ok) {
                const float* p = Af32 + (size_t)arow * DIM + kofs;
                float4 f0 = *(const float4*)(p);
                float4 f1 = *(const float4*)(p + 4);
                afrag = (short8){
                    (short)f32_to_bf16_rne(f0.x), (short)f32_to_bf16_rne(f0.y),
                    (short)f32_to_bf16_rne(f0.z), (short)f32_to_bf16_rne(f0.w),
                    (short)f32_to_bf16_rne(f1.x), (short)f32_to_bf16_rne(f1.y),
                    (short)f32_to_bf16_rne(f1.z), (short)f32_to_bf16_rne(f1.w)};
            } else afrag = (short8){0,0,0,0,0,0,0,0};
        }
        const unsigned short* wp = packW + ((size_t)ks * 8 * 64 + lane) * 8;
        #pragma unroll
        for (int nt = 0; nt < 8; nt++) {
            short8 wfrag = *(const short8*)(wp + (size_t)nt * 64 * 8);
            acc[nt] = __builtin_amdgcn_mfma_f32_16x16x32_bf16(afrag, wfrag, acc[nt], 0, 0, 0);
        }
    }
    #pragma unroll
    for (int nt = 0; nt < 8; nt++) {
        int col = nt * 16 + l15;
        float bv = bias[col];
        #pragma unroll
        for (int r = 0; r < 4; r++) {
            int row = m0 + quad * 4 + r;
            if (row < M) out[(size_t)row * DIM + col] = acc[nt][r] + bv;
        }
    }
}

extern "C" void kernel_launch(void* const* d_in, const int* in_sizes, int n_in,
                              void* d_out, int out_size, void* d_ws, size_t ws_size,
                              hipStream_t stream) {
    const float* x_user = (const float*)d_in[0];
    const float* x_item = (const float*)d_in[1];
    const float* x_tag  = (const float*)d_in[2];
    const int* ei_buys  = (const int*)d_in[3];
    const int* ei_rev   = (const int*)d_in[4];
    const int* ei_tags  = (const int*)d_in[5];
    const float* Wl_b = (const float*)d_in[6];
    const float* Wr_b = (const float*)d_in[7];
    const float* b_b  = (const float*)d_in[8];
    const float* Wl_r = (const float*)d_in[9];
    const float* Wr_r = (const float*)d_in[10];
    const float* b_r  = (const float*)d_in[11];
    const float* Wl_t = (const float*)d_in[12];
    const float* Wr_t = (const float*)d_in[13];
    const float* b_t  = (const float*)d_in[14];

    const int N  = NNODE;
    const int E0 = in_sizes[3] / 2, E1 = in_sizes[4] / 2, E2 = in_sizes[5] / 2;
    const int n_user = in_sizes[0], n_item = in_sizes[1], n_tag = in_sizes[2];

    // workspace layout (bytes)
    char* w = (char*)d_ws;
    int* cnt    = (int*)(w + 0);
    int* off    = (int*)(w + 1200000);
    int* cur    = (int*)(w + 2400000);
    int* sorted = (int*)(w + 3600000);
    unsigned short* msg = (unsigned short*)(w + 15600000);
    unsigned short* pw_item = (unsigned short*)(w + 92400000);
    unsigned short* pw_user = (unsigned short*)(w + 92498304);
    float* bias_item = (float*)(w + 92563840);
    float* bias_user = (float*)(w + 92564352);
    unsigned short* xb_user = (unsigned short*)(w + 92564992);
    unsigned short* xb_item = (unsigned short*)(w + 118164992);
    unsigned short* xb_tag  = (unsigned short*)(w + 143764992);
    const size_t NEED_BF16 = 146324992;
    const bool use_bf16x = ws_size >= NEED_BF16;   // constant across calls

    float* out_user = (float*)d_out;
    float* out_item = out_user + (size_t)N * DIM;

    int Etot = E0 + E1 + E2;

    hipMemsetAsync(cnt, 0, (size_t)3 * N * sizeof(int), stream);

    pack_kernel<<<(49152 + 32768 + 2 * DIM + 255) / 256, 256, 0, stream>>>(
        Wl_b, Wr_b, b_b, Wl_r, Wr_r, b_r, Wl_t, Wr_t, b_t,
        pw_item, pw_user, bias_item, bias_user);

    if (use_bf16x) {
        int tot4 = (n_user + n_item + n_tag) / 4;
        conv_kernel<<<(tot4 + 255) / 256, 256, 0, stream>>>(
            x_user, x_item, x_tag, xb_user, xb_item, xb_tag, n_user, n_item, n_tag);
    }

    hist_kernel<<<(Etot + 255) / 256, 256, 0, stream>>>(
        ei_buys + E0, ei_rev + E1, ei_tags + E2, E0, E1, E2, cnt, N);

    scan_kernel<<<3, 1024, 0, stream>>>(cnt, off, cur, N);

    scatter_kernel<<<(Etot + 255) / 256, 256, 0, stream>>>(
        ei_buys, ei_rev, ei_tags, E0, E1, E2, cur, sorted, N);

    if (use_bf16x) {
        agg_kernel_bf16<<<(3 * N * 64 + 255) / 256, 256, 0, stream>>>(
            xb_user, xb_item, xb_tag, sorted, off, cnt, E0, E0 + E1, msg, N);
        // out_item = msg_buys@(.5Wl_b) + msg_tags@(.5Wl_t) + x_item@(.5(Wr_b+Wr_t)) + bias
        gemm_kernel<<<(N + 63) / 64, 256, 0, stream>>>(
            msg, msg + 2 * (size_t)N * DIM, xb_item, nullptr, 3, 3,
            pw_item, bias_item, out_item, N);
        // out_user = msg_rev@Wl_r + x_user@Wr_r + b_r
        gemm_kernel<<<(N + 63) / 64, 256, 0, stream>>>(
            msg + (size_t)N * DIM, xb_user, nullptr, nullptr, 2, 2,
            pw_user, bias_user, out_user, N);
    } else {
        agg_kernel_f32<<<(3 * N * 64 + 255) / 256, 256, 0, stream>>>(
            x_user, x_item, x_tag, sorted, off, cnt, E0, E0 + E1, msg, N);
        gemm_kernel<<<(N + 63) / 64, 256, 0, stream>>>(
            msg, msg + 2 * (size_t)N * DIM, nullptr, x_item, 2, 3,
            pw_item, bias_item, out_item, N);
        gemm_kernel<<<(N + 63) / 64, 256, 0, stream>>>(
            msg + (size_t)N * DIM, nullptr, nullptr, x_user, 1, 2,
            pw_user, bias_user, out_user, N);
    }
}

// Round 3
// 513.516 us; speedup vs baseline: 2.1561x; 1.8056x over previous
//
#include <hip/hip_runtime.h>
#include <hip/hip_bf16.h>
#include <stdint.h>

#define DIM 128
#define NNODE 100000
#define NB 98            // coarse bins per relation (1024 dsts each)
#define NBT (3 * NB)     // 294
#define T_TILE 8192      // edges per coarse-scatter tile

typedef __attribute__((ext_vector_type(8))) short short8;
typedef __attribute__((ext_vector_type(4))) float f32x4;

__device__ __forceinline__ unsigned short f32_to_bf16_rne(float f) {
    union { float f; uint32_t u; } v; v.f = f;
    uint32_t u = v.u;
    uint32_t r = u + 0x7FFFu + ((u >> 16) & 1u);
    return (unsigned short)(r >> 16);
}
__device__ __forceinline__ float bf16lo_to_f32(uint32_t u) {
    union { uint32_t i; float f; } v; v.i = u << 16; return v.f;
}
__device__ __forceinline__ float bf16hi_to_f32(uint32_t u) {
    union { uint32_t i; float f; } v; v.i = u & 0xFFFF0000u; return v.f;
}

// ---------------- f32 -> bf16 table conversion ----------------
__global__ void conv_kernel(const float* __restrict__ xu, const float* __restrict__ xi,
                            const float* __restrict__ xt,
                            unsigned short* __restrict__ bu, unsigned short* __restrict__ bi,
                            unsigned short* __restrict__ bt, int nu, int ni, int nt) {
    int idx = blockIdx.x * blockDim.x + threadIdx.x;     // one float4 per thread
    int q_u = nu >> 2, q_i = ni >> 2, q_t = nt >> 2;
    const float* src; unsigned short* dst; int o;
    if (idx < q_u)                { src = xu; dst = bu; o = idx; }
    else if (idx < q_u + q_i)     { src = xi; dst = bi; o = idx - q_u; }
    else if (idx < q_u + q_i+q_t) { src = xt; dst = bt; o = idx - q_u - q_i; }
    else return;
    float4 f = ((const float4*)src)[o];
    ushort4 u;
    u.x = f32_to_bf16_rne(f.x); u.y = f32_to_bf16_rne(f.y);
    u.z = f32_to_bf16_rne(f.z); u.w = f32_to_bf16_rne(f.w);
    ((ushort4*)dst)[o] = u;
}

// ---------------- coarse histogram (LDS pre-aggregated) ----------------
__global__ __launch_bounds__(256) void coarse_hist(
    const int* __restrict__ ei0, const int* __restrict__ ei1, const int* __restrict__ ei2,
    int E0, int E1, int E2, int* __restrict__ ccnt) {
    __shared__ int h[NBT];
    int Etot = E0 + E1 + E2;
    for (int i = threadIdx.x; i < NBT; i += 256) h[i] = 0;
    __syncthreads();
    for (int e = blockIdx.x * blockDim.x + threadIdx.x; e < Etot; e += gridDim.x * blockDim.x) {
        int rel, le; const int* ei; int E;
        if (e < E0)           { rel = 0; le = e;           ei = ei0; E = E0; }
        else if (e < E0 + E1) { rel = 1; le = e - E0;      ei = ei1; E = E1; }
        else                  { rel = 2; le = e - E0 - E1; ei = ei2; E = E2; }
        int d = ei[E + le];
        atomicAdd(&h[rel * NB + (d >> 10)], 1);
    }
    __syncthreads();
    for (int i = threadIdx.x; i < NBT; i += 256) {
        int c = h[i];
        if (c) atomicAdd(&ccnt[i], c);
    }
}

// ---------------- coarse scan (tiny, 1 block) ----------------
__global__ void coarse_scan(const int* __restrict__ ccnt, int* __restrict__ bases,
                            int* __restrict__ cursor) {
    if (threadIdx.x == 0) {
        int run = 0;
        for (int i = 0; i < NBT; i++) {
            bases[i] = run; cursor[i] = run;
            run += ccnt[i];
        }
        bases[NBT] = run;
    }
}

// ---------------- coarse scatter: tiled, per-tile reserved runs ----------------
__global__ __launch_bounds__(256) void coarse_scatter(
    const int* __restrict__ ei0, const int* __restrict__ ei1, const int* __restrict__ ei2,
    int E0, int E1, int E2, int* __restrict__ cursor, int2* __restrict__ pairs) {
    __shared__ int h[NBT], hb[NBT], lc[NBT];
    int Etot = E0 + E1 + E2;
    int ntiles = (Etot + T_TILE - 1) / T_TILE;
    for (int tile = blockIdx.x; tile < ntiles; tile += gridDim.x) {
        int tbase = tile * T_TILE;
        for (int i = threadIdx.x; i < NBT; i += 256) { h[i] = 0; lc[i] = 0; }
        __syncthreads();
        int dstreg[32], srcreg[32];
        #pragma unroll
        for (int k = 0; k < 32; k++) {
            int e = tbase + k * 256 + threadIdx.x;
            dstreg[k] = -1;
            if (e < Etot) {
                int rel, le; const int* ei; int E;
                if (e < E0)           { rel = 0; le = e;           ei = ei0; E = E0; }
                else if (e < E0 + E1) { rel = 1; le = e - E0;      ei = ei1; E = E1; }
                else                  { rel = 2; le = e - E0 - E1; ei = ei2; E = E2; }
                int d = ei[E + le];
                srcreg[k] = ei[le];
                dstreg[k] = d;
                atomicAdd(&h[rel * NB + (d >> 10)], 1);
            }
        }
        __syncthreads();
        for (int i = threadIdx.x; i < NBT; i += 256) {
            int c = h[i];
            hb[i] = c ? atomicAdd(&cursor[i], c) : 0;
        }
        __syncthreads();
        #pragma unroll
        for (int k = 0; k < 32; k++) {
            int e = tbase + k * 256 + threadIdx.x;
            if (e < Etot) {
                int d = dstreg[k];
                int rel = (e < E0) ? 0 : ((e < E0 + E1) ? 1 : 2);
                int bin = rel * NB + (d >> 10);
                int pos = hb[bin] + atomicAdd(&lc[bin], 1);
                pairs[pos] = make_int2(srcreg[k], d);
            }
        }
        __syncthreads();
    }
}

// ---------------- fine sort: 1 block per coarse bucket; writes cnt/off/sorted --------
__global__ __launch_bounds__(256) void fine_sort(
    const int* __restrict__ bases, const int2* __restrict__ pairs,
    int* __restrict__ cnt, int* __restrict__ off, int* __restrict__ sorted, int N) {
    __shared__ int h[1024], ho[1024], ssum[256];
    int b = blockIdx.x;
    int rel = b / NB, jb = b - rel * NB;
    int ebase = bases[b], ne = bases[b + 1] - ebase;
    int dbase = jb << 10;
    int tid = threadIdx.x;
    for (int i = tid; i < 1024; i += 256) h[i] = 0;
    __syncthreads();
    for (int i = tid; i < ne; i += 256) {
        int d = pairs[ebase + i].y;
        atomicAdd(&h[d - dbase], 1);
    }
    __syncthreads();
    int v0 = h[tid * 4], v1 = h[tid * 4 + 1], v2 = h[tid * 4 + 2], v3 = h[tid * 4 + 3];
    int tsum = v0 + v1 + v2 + v3;
    ssum[tid] = tsum;
    __syncthreads();
    for (int s = 1; s < 256; s <<= 1) {
        int t = (tid >= s) ? ssum[tid - s] : 0;
        __syncthreads();
        ssum[tid] += t;
        __syncthreads();
    }
    int excl = ssum[tid] - tsum;
    ho[tid * 4] = excl;
    ho[tid * 4 + 1] = excl + v0;
    ho[tid * 4 + 2] = excl + v0 + v1;
    ho[tid * 4 + 3] = excl + v0 + v1 + v2;
    __syncthreads();
    for (int i = tid; i < 1024; i += 256) {
        int d = dbase + i;
        if (d < N) { cnt[rel * N + d] = h[i]; off[rel * N + d] = ebase + ho[i]; }
        h[i] = 0;   // becomes cursor
    }
    __syncthreads();
    for (int i = tid; i < ne; i += 256) {
        int2 p = pairs[ebase + i];
        int dl = p.y - dbase;
        int pos = ebase + ho[dl] + atomicAdd(&h[dl], 1);
        sorted[pos] = p.x;
    }
}

// ---------------- segment mean (bf16): quarter-wave rows, 8 rows in flight ----------
__global__ __launch_bounds__(256) void agg_kernel_bf16(
    const unsigned short* __restrict__ xb_user, const unsigned short* __restrict__ xb_item,
    const unsigned short* __restrict__ xb_tag,
    const int* __restrict__ sorted, const int* __restrict__ off,
    const int* __restrict__ cnt, unsigned short* __restrict__ msg, int N) {
    int w = (blockIdx.x * blockDim.x + threadIdx.x) >> 6;
    int lane = threadIdx.x & 63;
    if (w >= 3 * N) return;
    int rel = w / N;
    int d = w - rel * N;
    const unsigned short* xs = (rel == 0) ? xb_user : (rel == 1) ? xb_item : xb_tag;
    int start = off[rel * N + d];
    int deg = cnt[rel * N + d];
    const int* lst = sorted + start;
    int q = lane >> 4;          // quarter id: neighbor selector
    int c = lane & 15;          // 16 lanes x 16B = one 256B bf16 row
    float a0=0,a1=0,a2=0,a3=0,a4=0,a5=0,a6=0,a7=0;
    #define ACC(U) { \
        a0 += bf16lo_to_f32(U.x); a1 += bf16hi_to_f32(U.x); \
        a2 += bf16lo_to_f32(U.y); a3 += bf16hi_to_f32(U.y); \
        a4 += bf16lo_to_f32(U.z); a5 += bf16hi_to_f32(U.z); \
        a6 += bf16lo_to_f32(U.w); a7 += bf16hi_to_f32(U.w); }
    int i = 0;
    for (; i + 8 <= deg; i += 8) {
        int s0 = lst[i + q];
        int s1 = lst[i + 4 + q];
        uint4 u0 = *(const uint4*)(xs + (size_t)s0 * DIM + c * 8);
        uint4 u1 = *(const uint4*)(xs + (size_t)s1 * DIM + c * 8);
        ACC(u0); ACC(u1);
    }
    int rem = deg - i;          // 0..7
    if (q < rem) {
        int s = lst[i + q];
        uint4 u = *(const uint4*)(xs + (size_t)s * DIM + c * 8);
        ACC(u);
    }
    if (q + 4 < rem) {
        int s = lst[i + 4 + q];
        uint4 u = *(const uint4*)(xs + (size_t)s * DIM + c * 8);
        ACC(u);
    }
    #undef ACC
    a0 += __shfl_xor(a0, 16, 64); a1 += __shfl_xor(a1, 16, 64);
    a2 += __shfl_xor(a2, 16, 64); a3 += __shfl_xor(a3, 16, 64);
    a4 += __shfl_xor(a4, 16, 64); a5 += __shfl_xor(a5, 16, 64);
    a6 += __shfl_xor(a6, 16, 64); a7 += __shfl_xor(a7, 16, 64);
    a0 += __shfl_xor(a0, 32, 64); a1 += __shfl_xor(a1, 32, 64);
    a2 += __shfl_xor(a2, 32, 64); a3 += __shfl_xor(a3, 32, 64);
    a4 += __shfl_xor(a4, 32, 64); a5 += __shfl_xor(a5, 32, 64);
    a6 += __shfl_xor(a6, 32, 64); a7 += __shfl_xor(a7, 32, 64);
    if (q == 0) {
        float inv = 1.0f / (float)max(deg, 1);
        uint4 o;
        o.x = (uint32_t)f32_to_bf16_rne(a0 * inv) | ((uint32_t)f32_to_bf16_rne(a1 * inv) << 16);
        o.y = (uint32_t)f32_to_bf16_rne(a2 * inv) | ((uint32_t)f32_to_bf16_rne(a3 * inv) << 16);
        o.z = (uint32_t)f32_to_bf16_rne(a4 * inv) | ((uint32_t)f32_to_bf16_rne(a5 * inv) << 16);
        o.w = (uint32_t)f32_to_bf16_rne(a6 * inv) | ((uint32_t)f32_to_bf16_rne(a7 * inv) << 16);
        *(uint4*)(msg + (size_t)(rel * N + d) * DIM + c * 8) = o;
    }
}

// ---------------- pack weights into MFMA B-fragment order (bf16) + biases ----------------
__global__ void pack_kernel(const float* __restrict__ Wl_b, const float* __restrict__ Wr_b,
                            const float* __restrict__ b_b,
                            const float* __restrict__ Wl_r, const float* __restrict__ Wr_r,
                            const float* __restrict__ b_r,
                            const float* __restrict__ Wl_t, const float* __restrict__ Wr_t,
                            const float* __restrict__ b_t,
                            unsigned short* __restrict__ pw_item,
                            unsigned short* __restrict__ pw_user,
                            float* __restrict__ bias_item, float* __restrict__ bias_user) {
    const int NI = 12 * 8 * 64 * 8;   // item: K=384
    const int NU = 8 * 8 * 64 * 8;    // user: K=256
    int o = blockIdx.x * blockDim.x + threadIdx.x;
    if (o < NI) {
        int j = o & 7, lane = (o >> 3) & 63, ks = o >> 12;
        int n = ((o >> 9) & 7) * 16 + (lane & 15);
        int k = (ks & 3) * 32 + (lane >> 4) * 8 + j;
        int src = ks >> 2;
        float v;
        if (src == 0)      v = 0.5f * Wl_b[k * DIM + n];
        else if (src == 1) v = 0.5f * Wl_t[k * DIM + n];
        else               v = 0.5f * (Wr_b[k * DIM + n] + Wr_t[k * DIM + n]);
        pw_item[o] = f32_to_bf16_rne(v);
    } else if (o < NI + NU) {
        int oo = o - NI;
        int j = oo & 7, lane = (oo >> 3) & 63, ks = oo >> 12;
        int n = ((oo >> 9) & 7) * 16 + (lane & 15);
        int k = (ks & 3) * 32 + (lane >> 4) * 8 + j;
        float v = ((ks >> 2) == 0) ? Wl_r[k * DIM + n] : Wr_r[k * DIM + n];
        pw_user[oo] = f32_to_bf16_rne(v);
    } else {
        int oo = o - NI - NU;
        if (oo < DIM)            bias_item[oo] = 0.5f * (b_b[oo] + b_t[oo]);
        else if (oo < 2 * DIM)   bias_user[oo - DIM] = b_r[oo - DIM];
    }
}

// ---------------- fused GEMM: out = [A0|A1|A2] @ packW + bias ----------------
__global__ __launch_bounds__(256) void gemm_kernel(
    const unsigned short* __restrict__ Abf0,
    const unsigned short* __restrict__ Abf1,
    const unsigned short* __restrict__ Abf2,
    int n_src,
    const unsigned short* __restrict__ packW,
    const float* __restrict__ bias,
    float* __restrict__ out, int M) {
    int wave = threadIdx.x >> 6;
    int lane = threadIdx.x & 63;
    int quad = lane >> 4;
    int l15  = lane & 15;
    int m0   = blockIdx.x * 64 + wave * 16;
    int arow = m0 + l15;
    bool arow_ok = arow < M;
    int nks = n_src * 4;

    f32x4 acc[8];
    #pragma unroll
    for (int i = 0; i < 8; i++) acc[i] = (f32x4){0.f, 0.f, 0.f, 0.f};

    for (int ks = 0; ks < nks; ks++) {
        int src = ks >> 2;
        int kofs = (ks & 3) * 32 + quad * 8;
        short8 afrag;
        const unsigned short* A = (src == 0) ? Abf0 : (src == 1) ? Abf1 : Abf2;
        if (arow_ok) afrag = *(const short8*)(A + (size_t)arow * DIM + kofs);
        else         afrag = (short8){0,0,0,0,0,0,0,0};
        const unsigned short* wp = packW + ((size_t)ks * 8 * 64 + lane) * 8;
        #pragma unroll
        for (int nt = 0; nt < 8; nt++) {
            short8 wfrag = *(const short8*)(wp + (size_t)nt * 64 * 8);
            acc[nt] = __builtin_amdgcn_mfma_f32_16x16x32_bf16(afrag, wfrag, acc[nt], 0, 0, 0);
        }
    }
    #pragma unroll
    for (int nt = 0; nt < 8; nt++) {
        int col = nt * 16 + l15;
        float bv = bias[col];
        #pragma unroll
        for (int r = 0; r < 4; r++) {
            int row = m0 + quad * 4 + r;
            if (row < M) out[(size_t)row * DIM + col] = acc[nt][r] + bv;
        }
    }
}

extern "C" void kernel_launch(void* const* d_in, const int* in_sizes, int n_in,
                              void* d_out, int out_size, void* d_ws, size_t ws_size,
                              hipStream_t stream) {
    const float* x_user = (const float*)d_in[0];
    const float* x_item = (const float*)d_in[1];
    const float* x_tag  = (const float*)d_in[2];
    const int* ei_buys  = (const int*)d_in[3];
    const int* ei_rev   = (const int*)d_in[4];
    const int* ei_tags  = (const int*)d_in[5];
    const float* Wl_b = (const float*)d_in[6];
    const float* Wr_b = (const float*)d_in[7];
    const float* b_b  = (const float*)d_in[8];
    const float* Wl_r = (const float*)d_in[9];
    const float* Wr_r = (const float*)d_in[10];
    const float* b_r  = (const float*)d_in[11];
    const float* Wl_t = (const float*)d_in[12];
    const float* Wr_t = (const float*)d_in[13];
    const float* b_t  = (const float*)d_in[14];

    const int N  = NNODE;
    const int E0 = in_sizes[3] / 2, E1 = in_sizes[4] / 2, E2 = in_sizes[5] / 2;
    const int n_user = in_sizes[0], n_item = in_sizes[1], n_tag = in_sizes[2];

    // workspace layout (bytes), total <= 146,324,992 (proven available)
    char* w = (char*)d_ws;
    int* cnt    = (int*)(w + 0);                 // 1,200,000
    int* off    = (int*)(w + 1200000);           // 1,200,000
    int* ccnt   = (int*)(w + 2400000);           // 294*4
    int* bases  = (int*)(w + 2401280);           // 295*4
    int* cursor = (int*)(w + 2402560);           // 294*4
    int* sorted = (int*)(w + 2403840);           // 12,000,000
    unsigned short* msg = (unsigned short*)(w + 15600000);       // 76,800,000
    int2* pairs = (int2*)(w + 15600000);         // 24,000,000 — aliases msg (dead until agg)
    unsigned short* pw_item = (unsigned short*)(w + 92400000);
    unsigned short* pw_user = (unsigned short*)(w + 92498304);
    float* bias_item = (float*)(w + 92563840);
    float* bias_user = (float*)(w + 92564352);
    unsigned short* xb_user = (unsigned short*)(w + 92564992);
    unsigned short* xb_item = (unsigned short*)(w + 118164992);
    unsigned short* xb_tag  = (unsigned short*)(w + 143764992);  // end 146,324,992

    float* out_user = (float*)d_out;
    float* out_item = out_user + (size_t)N * DIM;

    int Etot = E0 + E1 + E2;

    hipMemsetAsync(ccnt, 0, NBT * sizeof(int), stream);

    pack_kernel<<<(49152 + 32768 + 2 * DIM + 255) / 256, 256, 0, stream>>>(
        Wl_b, Wr_b, b_b, Wl_r, Wr_r, b_r, Wl_t, Wr_t, b_t,
        pw_item, pw_user, bias_item, bias_user);

    int tot4 = (n_user + n_item + n_tag) / 4;
    conv_kernel<<<(tot4 + 255) / 256, 256, 0, stream>>>(
        x_user, x_item, x_tag, xb_user, xb_item, xb_tag, n_user, n_item, n_tag);

    coarse_hist<<<512, 256, 0, stream>>>(ei_buys, ei_rev, ei_tags, E0, E1, E2, ccnt);

    coarse_scan<<<1, 64, 0, stream>>>(ccnt, bases, cursor);

    int ntiles = (Etot + T_TILE - 1) / T_TILE;
    coarse_scatter<<<ntiles, 256, 0, stream>>>(
        ei_buys, ei_rev, ei_tags, E0, E1, E2, cursor, pairs);

    fine_sort<<<NBT, 256, 0, stream>>>(bases, pairs, cnt, off, sorted, N);

    agg_kernel_bf16<<<(3 * N * 64 + 255) / 256, 256, 0, stream>>>(
        xb_user, xb_item, xb_tag, sorted, off, cnt, msg, N);

    // out_item = msg_buys@(.5Wl_b) + msg_tags@(.5Wl_t) + x_item@(.5(Wr_b+Wr_t)) + bias
    gemm_kernel<<<(N + 63) / 64, 256, 0, stream>>>(
        msg, msg + 2 * (size_t)N * DIM, xb_item, 3, pw_item, bias_item, out_item, N);

    // out_user = msg_rev@Wl_r + x_user@Wr_r + b_r
    gemm_kernel<<<(N + 63) / 64, 256, 0, stream>>>(
        msg + (size_t)N * DIM, xb_user, nullptr, 2, pw_user, bias_user, out_user, N);
}

// Round 4
// 504.666 us; speedup vs baseline: 2.1939x; 1.0175x over previous
//
#include <hip/hip_runtime.h>
#include <hip/hip_bf16.h>
#include <stdint.h>

#define DIM 128
#define NNODE 100000
#define NB 98            // coarse bins per relation (1024 dsts each)
#define NBT (3 * NB)     // 294
#define T_TILE 8192      // edges per coarse-scatter tile

typedef __attribute__((ext_vector_type(8))) short short8;
typedef __attribute__((ext_vector_type(4))) float f32x4;

__device__ __forceinline__ unsigned short f32_to_bf16_rne(float f) {
    union { float f; uint32_t u; } v; v.f = f;
    uint32_t u = v.u;
    uint32_t r = u + 0x7FFFu + ((u >> 16) & 1u);
    return (unsigned short)(r >> 16);
}
__device__ __forceinline__ float bf16lo_to_f32(uint32_t u) {
    union { uint32_t i; float f; } v; v.i = u << 16; return v.f;
}
__device__ __forceinline__ float bf16hi_to_f32(uint32_t u) {
    union { uint32_t i; float f; } v; v.i = u & 0xFFFF0000u; return v.f;
}

// ---------------- f32 -> bf16 table conversion ----------------
__global__ void conv_kernel(const float* __restrict__ xu, const float* __restrict__ xi,
                            const float* __restrict__ xt,
                            unsigned short* __restrict__ bu, unsigned short* __restrict__ bi,
                            unsigned short* __restrict__ bt, int nu, int ni, int nt) {
    int idx = blockIdx.x * blockDim.x + threadIdx.x;     // one float4 per thread
    int q_u = nu >> 2, q_i = ni >> 2, q_t = nt >> 2;
    const float* src; unsigned short* dst; int o;
    if (idx < q_u)                { src = xu; dst = bu; o = idx; }
    else if (idx < q_u + q_i)     { src = xi; dst = bi; o = idx - q_u; }
    else if (idx < q_u + q_i+q_t) { src = xt; dst = bt; o = idx - q_u - q_i; }
    else return;
    float4 f = ((const float4*)src)[o];
    ushort4 u;
    u.x = f32_to_bf16_rne(f.x); u.y = f32_to_bf16_rne(f.y);
    u.z = f32_to_bf16_rne(f.z); u.w = f32_to_bf16_rne(f.w);
    ((ushort4*)dst)[o] = u;
}

// ---------------- coarse histogram (LDS pre-aggregated) ----------------
__global__ __launch_bounds__(256) void coarse_hist(
    const int* __restrict__ ei0, const int* __restrict__ ei1, const int* __restrict__ ei2,
    int E0, int E1, int E2, int* __restrict__ ccnt) {
    __shared__ int h[NBT];
    int Etot = E0 + E1 + E2;
    for (int i = threadIdx.x; i < NBT; i += 256) h[i] = 0;
    __syncthreads();
    for (int e = blockIdx.x * blockDim.x + threadIdx.x; e < Etot; e += gridDim.x * blockDim.x) {
        int rel, le; const int* ei; int E;
        if (e < E0)           { rel = 0; le = e;           ei = ei0; E = E0; }
        else if (e < E0 + E1) { rel = 1; le = e - E0;      ei = ei1; E = E1; }
        else                  { rel = 2; le = e - E0 - E1; ei = ei2; E = E2; }
        int d = ei[E + le];
        atomicAdd(&h[rel * NB + (d >> 10)], 1);
    }
    __syncthreads();
    for (int i = threadIdx.x; i < NBT; i += 256) {
        int c = h[i];
        if (c) atomicAdd(&ccnt[i], c);
    }
}

// ---------------- coarse scan (tiny, 1 block) ----------------
__global__ void coarse_scan(const int* __restrict__ ccnt, int* __restrict__ bases,
                            int* __restrict__ cursor) {
    if (threadIdx.x == 0) {
        int run = 0;
        for (int i = 0; i < NBT; i++) {
            bases[i] = run; cursor[i] = run;
            run += ccnt[i];
        }
        bases[NBT] = run;
    }
}

// ---------------- coarse scatter: tiled, per-tile reserved runs; packed pairs -------
// pair encoding: src (17 bits) | dst_local (10 bits) << 17
__global__ __launch_bounds__(256) void coarse_scatter(
    const int* __restrict__ ei0, const int* __restrict__ ei1, const int* __restrict__ ei2,
    int E0, int E1, int E2, int* __restrict__ cursor, int* __restrict__ pairs) {
    __shared__ int h[NBT], hb[NBT], lc[NBT];
    int Etot = E0 + E1 + E2;
    int ntiles = (Etot + T_TILE - 1) / T_TILE;
    for (int tile = blockIdx.x; tile < ntiles; tile += gridDim.x) {
        int tbase = tile * T_TILE;
        for (int i = threadIdx.x; i < NBT; i += 256) { h[i] = 0; lc[i] = 0; }
        __syncthreads();
        int binreg[32], valreg[32];
        #pragma unroll
        for (int k = 0; k < 32; k++) {
            int e = tbase + k * 256 + threadIdx.x;
            binreg[k] = -1;
            if (e < Etot) {
                int rel, le; const int* ei; int E;
                if (e < E0)           { rel = 0; le = e;           ei = ei0; E = E0; }
                else if (e < E0 + E1) { rel = 1; le = e - E0;      ei = ei1; E = E1; }
                else                  { rel = 2; le = e - E0 - E1; ei = ei2; E = E2; }
                int d = ei[E + le];
                int s = ei[le];
                int bin = rel * NB + (d >> 10);
                binreg[k] = bin;
                valreg[k] = s | ((d & 1023) << 17);
                atomicAdd(&h[bin], 1);
            }
        }
        __syncthreads();
        for (int i = threadIdx.x; i < NBT; i += 256) {
            int c = h[i];
            hb[i] = c ? atomicAdd(&cursor[i], c) : 0;
        }
        __syncthreads();
        #pragma unroll
        for (int k = 0; k < 32; k++) {
            if (binreg[k] >= 0) {
                int bin = binreg[k];
                int pos = hb[bin] + atomicAdd(&lc[bin], 1);
                pairs[pos] = valreg[k];
            }
        }
        __syncthreads();
    }
}

// ---------------- fine sort: 1 block per coarse bucket; writes off/sorted ----------
__global__ __launch_bounds__(256) void fine_sort(
    const int* __restrict__ bases, const int* __restrict__ pairs,
    int* __restrict__ off, int* __restrict__ sorted, int N) {
    __shared__ int h[1024], ho[1024], ssum[256];
    int b = blockIdx.x;
    int rel = b / NB, jb = b - rel * NB;
    int ebase = bases[b], ne = bases[b + 1] - ebase;
    int dbase = jb << 10;
    int tid = threadIdx.x;
    for (int i = tid; i < 1024; i += 256) h[i] = 0;
    __syncthreads();
    for (int i = tid; i < ne; i += 256) {
        int dl = pairs[ebase + i] >> 17;
        atomicAdd(&h[dl], 1);
    }
    __syncthreads();
    int v0 = h[tid * 4], v1 = h[tid * 4 + 1], v2 = h[tid * 4 + 2], v3 = h[tid * 4 + 3];
    int tsum = v0 + v1 + v2 + v3;
    ssum[tid] = tsum;
    __syncthreads();
    for (int s = 1; s < 256; s <<= 1) {
        int t = (tid >= s) ? ssum[tid - s] : 0;
        __syncthreads();
        ssum[tid] += t;
        __syncthreads();
    }
    int excl = ssum[tid] - tsum;
    ho[tid * 4] = excl;
    ho[tid * 4 + 1] = excl + v0;
    ho[tid * 4 + 2] = excl + v0 + v1;
    ho[tid * 4 + 3] = excl + v0 + v1 + v2;
    __syncthreads();
    for (int i = tid; i < 1024; i += 256) {
        int d = dbase + i;
        if (d < N) off[rel * N + d] = ebase + ho[i];
        h[i] = 0;   // becomes cursor
    }
    __syncthreads();
    for (int i = tid; i < ne; i += 256) {
        int p = pairs[ebase + i];
        int dl = p >> 17;
        int pos = ebase + ho[dl] + atomicAdd(&h[dl], 1);
        sorted[pos] = p & 0x1FFFF;
    }
}

// ---------------- segment mean (bf16): half-wave per dst, no cross-lane reduce ------
// 32 lanes x 8B (uint2 = 4 bf16) = one 256B row per half-wave; lane owns cols 4c..4c+3.
// 4-way neighbor unroll into independent accumulators; deg = off[g+1]-off[g].
__global__ __launch_bounds__(256) void agg_kernel_bf16(
    const unsigned short* __restrict__ xb_user, const unsigned short* __restrict__ xb_item,
    const unsigned short* __restrict__ xb_tag,
    const int* __restrict__ sorted, const int* __restrict__ off,
    unsigned short* __restrict__ msg, int N, int Etot) {
    int w = (blockIdx.x * blockDim.x + threadIdx.x) >> 6;
    int lane = threadIdx.x & 63;
    int hh = lane >> 5;          // half id
    int c = lane & 31;           // column group: elems 4c..4c+3
    int g = w * 2 + hh;          // global dst index (never straddles rel: N even)
    if (g >= 3 * N) return;
    int rel = g / N;
    const unsigned short* xs = (rel == 0) ? xb_user : (rel == 1) ? xb_item : xb_tag;
    int o0 = off[g];
    int o1 = (g + 1 < 3 * N) ? off[g + 1] : Etot;
    int deg = o1 - o0;
    const int* lst = sorted + o0;
    int c4 = c * 4;              // element offset within row
    f32x4 a0 = (f32x4){0,0,0,0}, a1 = (f32x4){0,0,0,0};
    f32x4 a2 = (f32x4){0,0,0,0}, a3 = (f32x4){0,0,0,0};
    #define ACCUM(A, U) { \
        A[0] += bf16lo_to_f32(U.x); A[1] += bf16hi_to_f32(U.x); \
        A[2] += bf16lo_to_f32(U.y); A[3] += bf16hi_to_f32(U.y); }
    int i = 0;
    for (; i + 4 <= deg; i += 4) {
        int s0 = lst[i], s1 = lst[i + 1], s2 = lst[i + 2], s3 = lst[i + 3];
        uint2 u0 = *(const uint2*)(xs + (size_t)s0 * DIM + c4);
        uint2 u1 = *(const uint2*)(xs + (size_t)s1 * DIM + c4);
        uint2 u2 = *(const uint2*)(xs + (size_t)s2 * DIM + c4);
        uint2 u3 = *(const uint2*)(xs + (size_t)s3 * DIM + c4);
        ACCUM(a0, u0); ACCUM(a1, u1); ACCUM(a2, u2); ACCUM(a3, u3);
    }
    for (; i < deg; i++) {
        int s0 = lst[i];
        uint2 u0 = *(const uint2*)(xs + (size_t)s0 * DIM + c4);
        ACCUM(a0, u0);
    }
    #undef ACCUM
    f32x4 s = (a0 + a1) + (a2 + a3);
    float inv = 1.0f / (float)max(deg, 1);
    uint2 o;
    o.x = (uint32_t)f32_to_bf16_rne(s[0] * inv) | ((uint32_t)f32_to_bf16_rne(s[1] * inv) << 16);
    o.y = (uint32_t)f32_to_bf16_rne(s[2] * inv) | ((uint32_t)f32_to_bf16_rne(s[3] * inv) << 16);
    *(uint2*)(msg + (size_t)g * DIM + c4) = o;
}

// ---------------- pack weights into MFMA B-fragment order (bf16) + biases ----------------
__global__ void pack_kernel(const float* __restrict__ Wl_b, const float* __restrict__ Wr_b,
                            const float* __restrict__ b_b,
                            const float* __restrict__ Wl_r, const float* __restrict__ Wr_r,
                            const float* __restrict__ b_r,
                            const float* __restrict__ Wl_t, const float* __restrict__ Wr_t,
                            const float* __restrict__ b_t,
                            unsigned short* __restrict__ pw_item,
                            unsigned short* __restrict__ pw_user,
                            float* __restrict__ bias_item, float* __restrict__ bias_user) {
    const int NI = 12 * 8 * 64 * 8;   // item: K=384
    const int NU = 8 * 8 * 64 * 8;    // user: K=256
    int o = blockIdx.x * blockDim.x + threadIdx.x;
    if (o < NI) {
        int j = o & 7, lane = (o >> 3) & 63, ks = o >> 12;
        int n = ((o >> 9) & 7) * 16 + (lane & 15);
        int k = (ks & 3) * 32 + (lane >> 4) * 8 + j;
        int src = ks >> 2;
        float v;
        if (src == 0)      v = 0.5f * Wl_b[k * DIM + n];
        else if (src == 1) v = 0.5f * Wl_t[k * DIM + n];
        else               v = 0.5f * (Wr_b[k * DIM + n] + Wr_t[k * DIM + n]);
        pw_item[o] = f32_to_bf16_rne(v);
    } else if (o < NI + NU) {
        int oo = o - NI;
        int j = oo & 7, lane = (oo >> 3) & 63, ks = oo >> 12;
        int n = ((oo >> 9) & 7) * 16 + (lane & 15);
        int k = (ks & 3) * 32 + (lane >> 4) * 8 + j;
        float v = ((ks >> 2) == 0) ? Wl_r[k * DIM + n] : Wr_r[k * DIM + n];
        pw_user[oo] = f32_to_bf16_rne(v);
    } else {
        int oo = o - NI - NU;
        if (oo < DIM)            bias_item[oo] = 0.5f * (b_b[oo] + b_t[oo]);
        else if (oo < 2 * DIM)   bias_user[oo - DIM] = b_r[oo - DIM];
    }
}

// ---------------- fused GEMM: out = [A0|A1|A2] @ packW + bias ----------------
__global__ __launch_bounds__(256) void gemm_kernel(
    const unsigned short* __restrict__ Abf0,
    const unsigned short* __restrict__ Abf1,
    const unsigned short* __restrict__ Abf2,
    int n_src,
    const unsigned short* __restrict__ packW,
    const float* __restrict__ bias,
    float* __restrict__ out, int M) {
    int wave = threadIdx.x >> 6;
    int lane = threadIdx.x & 63;
    int quad = lane >> 4;
    int l15  = lane & 15;
    int m0   = blockIdx.x * 64 + wave * 16;
    int arow = m0 + l15;
    bool arow_ok = arow < M;
    int nks = n_src * 4;

    f32x4 acc[8];
    #pragma unroll
    for (int i = 0; i < 8; i++) acc[i] = (f32x4){0.f, 0.f, 0.f, 0.f};

    for (int ks = 0; ks < nks; ks++) {
        int src = ks >> 2;
        int kofs = (ks & 3) * 32 + quad * 8;
        short8 afrag;
        const unsigned short* A = (src == 0) ? Abf0 : (src == 1) ? Abf1 : Abf2;
        if (arow_ok) afrag = *(const short8*)(A + (size_t)arow * DIM + kofs);
        else         afrag = (short8){0,0,0,0,0,0,0,0};
        const unsigned short* wp = packW + ((size_t)ks * 8 * 64 + lane) * 8;
        #pragma unroll
        for (int nt = 0; nt < 8; nt++) {
            short8 wfrag = *(const short8*)(wp + (size_t)nt * 64 * 8);
            acc[nt] = __builtin_amdgcn_mfma_f32_16x16x32_bf16(afrag, wfrag, acc[nt], 0, 0, 0);
        }
    }
    #pragma unroll
    for (int nt = 0; nt < 8; nt++) {
        int col = nt * 16 + l15;
        float bv = bias[col];
        #pragma unroll
        for (int r = 0; r < 4; r++) {
            int row = m0 + quad * 4 + r;
            if (row < M) out[(size_t)row * DIM + col] = acc[nt][r] + bv;
        }
    }
}

extern "C" void kernel_launch(void* const* d_in, const int* in_sizes, int n_in,
                              void* d_out, int out_size, void* d_ws, size_t ws_size,
                              hipStream_t stream) {
    const float* x_user = (const float*)d_in[0];
    const float* x_item = (const float*)d_in[1];
    const float* x_tag  = (const float*)d_in[2];
    const int* ei_buys  = (const int*)d_in[3];
    const int* ei_rev   = (const int*)d_in[4];
    const int* ei_tags  = (const int*)d_in[5];
    const float* Wl_b = (const float*)d_in[6];
    const float* Wr_b = (const float*)d_in[7];
    const float* b_b  = (const float*)d_in[8];
    const float* Wl_r = (const float*)d_in[9];
    const float* Wr_r = (const float*)d_in[10];
    const float* b_r  = (const float*)d_in[11];
    const float* Wl_t = (const float*)d_in[12];
    const float* Wr_t = (const float*)d_in[13];
    const float* b_t  = (const float*)d_in[14];

    const int N  = NNODE;
    const int E0 = in_sizes[3] / 2, E1 = in_sizes[4] / 2, E2 = in_sizes[5] / 2;
    const int n_user = in_sizes[0], n_item = in_sizes[1], n_tag = in_sizes[2];

    // workspace layout (bytes), total <= 146,324,992 (proven available)
    char* w = (char*)d_ws;
    int* off    = (int*)(w + 1200000);           // 1,200,000 (3N + pad)
    int* ccnt   = (int*)(w + 2400000);           // 294*4
    int* bases  = (int*)(w + 2401280);           // 295*4
    int* cursor = (int*)(w + 2402560);           // 294*4
    int* sorted = (int*)(w + 2403840);           // 12,000,000
    unsigned short* msg = (unsigned short*)(w + 15600000);       // 76,800,000
    int* pairs  = (int*)(w + 15600000);          // 12,000,000 — aliases msg (dead until agg)
    unsigned short* pw_item = (unsigned short*)(w + 92400000);
    unsigned short* pw_user = (unsigned short*)(w + 92498304);
    float* bias_item = (float*)(w + 92563840);
    float* bias_user = (float*)(w + 92564352);
    unsigned short* xb_user = (unsigned short*)(w + 92564992);
    unsigned short* xb_item = (unsigned short*)(w + 118164992);
    unsigned short* xb_tag  = (unsigned short*)(w + 143764992);  // end 146,324,992

    float* out_user = (float*)d_out;
    float* out_item = out_user + (size_t)N * DIM;

    int Etot = E0 + E1 + E2;

    hipMemsetAsync(ccnt, 0, NBT * sizeof(int), stream);

    pack_kernel<<<(49152 + 32768 + 2 * DIM + 255) / 256, 256, 0, stream>>>(
        Wl_b, Wr_b, b_b, Wl_r, Wr_r, b_r, Wl_t, Wr_t, b_t,
        pw_item, pw_user, bias_item, bias_user);

    int tot4 = (n_user + n_item + n_tag) / 4;
    conv_kernel<<<(tot4 + 255) / 256, 256, 0, stream>>>(
        x_user, x_item, x_tag, xb_user, xb_item, xb_tag, n_user, n_item, n_tag);

    coarse_hist<<<512, 256, 0, stream>>>(ei_buys, ei_rev, ei_tags, E0, E1, E2, ccnt);

    coarse_scan<<<1, 64, 0, stream>>>(ccnt, bases, cursor);

    int ntiles = (Etot + T_TILE - 1) / T_TILE;
    coarse_scatter<<<ntiles, 256, 0, stream>>>(
        ei_buys, ei_rev, ei_tags, E0, E1, E2, cursor, pairs);

    fine_sort<<<NBT, 256, 0, stream>>>(bases, pairs, off, sorted, N);

    // half-wave per dst: 3N dsts, 2 per wave -> 3N/2 waves
    int nwaves = (3 * N + 1) / 2;
    agg_kernel_bf16<<<(nwaves * 64 + 255) / 256, 256, 0, stream>>>(
        xb_user, xb_item, xb_tag, sorted, off, msg, N, Etot);

    // out_item = msg_buys@(.5Wl_b) + msg_tags@(.5Wl_t) + x_item@(.5(Wr_b+Wr_t)) + bias
    gemm_kernel<<<(N + 63) / 64, 256, 0, stream>>>(
        msg, msg + 2 * (size_t)N * DIM, xb_item, 3, pw_item, bias_item, out_item, N);

    // out_user = msg_rev@Wl_r + x_user@Wr_r + b_r
    gemm_kernel<<<(N + 63) / 64, 256, 0, stream>>>(
        msg + (size_t)N * DIM, xb_user, nullptr, 2, pw_user, bias_user, out_user, N);
}